// Round 15
// baseline (697.579 us; speedup 1.0000x reference)
//
#include <hip/hip_runtime.h>
#include <hip/hip_bf16.h>
#include <math.h>

typedef __hip_bfloat16 bf16;
typedef short bf16x8 __attribute__((ext_vector_type(8)));
typedef float f32x4 __attribute__((ext_vector_type(4)));
typedef float f32x16 __attribute__((ext_vector_type(16)));
typedef unsigned int u32;
typedef unsigned short u16;

#define GLD16(g, l)                                                            \
  __builtin_amdgcn_global_load_lds(                                            \
      (const __attribute__((address_space(1))) void*)(g),                      \
      (__attribute__((address_space(3))) void*)(l), 16, 0, 0)

#define SBAR() __builtin_amdgcn_s_barrier()
#define VMCNT(n) asm volatile("s_waitcnt vmcnt(" #n ")")
#define LGKM0() asm volatile("s_waitcnt lgkmcnt(0)")

// ------------------------------------------------------- f32 -> bf16 copy
__global__ void convert_f32_bf16(const float* __restrict__ in,
                                 bf16* __restrict__ out) {
  size_t i = ((size_t)blockIdx.x * 256 + threadIdx.x) * 4;
  float4 v = *(const float4*)(in + i);
  out[i + 0] = __float2bfloat16(v.x);
  out[i + 1] = __float2bfloat16(v.y);
  out[i + 2] = __float2bfloat16(v.z);
  out[i + 3] = __float2bfloat16(v.w);
}

// ----------------------------------------- f32 -> bf16 transposed weights
__global__ void transpose_f32_bf16(const float* __restrict__ in,
                                   bf16* __restrict__ out, int R, int C) {
  __shared__ bf16 tile[32][33];
  int tx = threadIdx.x & 31, ty = threadIdx.x >> 5;
  int c0 = blockIdx.x * 32, r0 = blockIdx.y * 32;
#pragma unroll
  for (int i = 0; i < 32; i += 8)
    tile[ty + i][tx] = __float2bfloat16(in[(size_t)(r0 + ty + i) * C + c0 + tx]);
  __syncthreads();
#pragma unroll
  for (int i = 0; i < 32; i += 8)
    out[(size_t)(c0 + ty + i) * R + r0 + tx] = tile[tx][ty + i];
}

// V block of QKV: [4096][6144] -> VT: [16][128][2048]
__global__ void transpose_v(const bf16* __restrict__ V, bf16* __restrict__ VT) {
  __shared__ bf16 tile[32][33];
  int s = blockIdx.z, b = s >> 3, kvh = s & 7;
  int t0 = blockIdx.x * 32, d0 = blockIdx.y * 32;
  int tx = threadIdx.x & 31, ty = threadIdx.x >> 5;
#pragma unroll
  for (int i = 0; i < 32; i += 8)
    tile[ty + i][tx] =
        V[(size_t)(b * 2048 + t0 + ty + i) * 6144 + kvh * 128 + d0 + tx];
  __syncthreads();
#pragma unroll
  for (int i = 0; i < 32; i += 8)
    VT[((size_t)s * 128 + d0 + ty + i) * 2048 + t0 + tx] = tile[tx][ty + i];
}

// ---------------------------------------------------------------- RoPE
__global__ void rope_table_k(float* __restrict__ tab) {
  int idx = blockIdx.x * 256 + threadIdx.x;  // t*64 + i
  int t = idx >> 6, i = idx & 63;
  float theta = powf(10000.0f, -2.0f * (float)i / 128.0f);
  float ang = (float)t * theta;
  tab[idx * 2 + 0] = cosf(ang);
  tab[idx * 2 + 1] = sinf(ang);
}

__global__ void rope_apply(bf16* __restrict__ X, const float* __restrict__ tab,
                           int nheads, int rowstride, float omul) {
  size_t idx = (size_t)blockIdx.x * 256 + threadIdx.x;
  int i = (int)(idx & 63);
  size_t rest = idx >> 6;
  int h = (int)(rest % nheads);
  size_t r = rest / nheads;
  int t = (int)(r & 2047);
  float c = tab[(t * 64 + i) * 2 + 0];
  float s = tab[(t * 64 + i) * 2 + 1];
  bf16* p = X + r * (size_t)rowstride + h * 128 + 2 * i;
  float xr = __bfloat162float(p[0]), xi = __bfloat162float(p[1]);
  p[0] = __float2bfloat16((xr * c - xi * s) * omul);
  p[1] = __float2bfloat16((xr * s + xi * c) * omul);
}

// ------------------------------------------------ GEMM 4-phase 256x256 BK=64
// (measured best: QKV 242 us at 384 blocks, O-proj at 256 blocks)
template <typename OutT>
__global__ __launch_bounds__(512, 2) void gemm_bt8(const bf16* __restrict__ A,
                                                   const bf16* __restrict__ BT,
                                                   OutT* __restrict__ C, int M,
                                                   int N, int K) {
  __shared__ bf16 AS[2][2][128 * 64];
  __shared__ bf16 BS[2][2][128 * 64];

  const int tid = threadIdx.x;
  const int lane = tid & 63;
  const int w = tid >> 6, wm = w >> 2, wn = w & 3;
  const int lr = lane & 15, hi = lane >> 4;

  int gx = gridDim.x;
  int nwg = gx * gridDim.y;
  int bid = blockIdx.y * gx + blockIdx.x;
  int swz = (bid & 7) * (nwg >> 3) + (bid >> 3);
  const int m0 = (swz / gx) * 256, n0 = (swz % gx) * 256;

  const int NKT = K >> 6;
  const int NI = K >> 7;
  const int srow = tid >> 3;
  const int scol = ((tid & 7) ^ (srow & 7)) << 3;

  f32x4 acc[8][4];
#pragma unroll
  for (int m = 0; m < 8; ++m)
#pragma unroll
    for (int n = 0; n < 4; ++n)
#pragma unroll
      for (int j = 0; j < 4; ++j) acc[m][n][j] = 0.f;

  auto STAGE_A = [&](int buf, int kt) {
    int kk0 = (kt < NKT) ? kt * 64 : 0;
#pragma unroll
    for (int hs = 0; hs < 4; ++hs) {
      int ha = hs >> 1, sa = hs & 1;
      const bf16* g = A + (size_t)(m0 + ha * 128 + sa * 64 + srow) * K + kk0 + scol;
      GLD16(g, &AS[buf][ha][(sa * 64 + srow) * 64 + (tid & 7) * 8]);
    }
  };
  auto STAGE_B = [&](int buf, int kt, int half) {
    int kk0 = (kt < NKT) ? kt * 64 : 0;
#pragma unroll
    for (int sa = 0; sa < 2; ++sa) {
      const bf16* g =
          BT + (size_t)(n0 + half * 128 + sa * 64 + srow) * K + kk0 + scol;
      GLD16(g, &BS[buf][half][(sa * 64 + srow) * 64 + (tid & 7) * 8]);
    }
  };

  bf16x8 bfr[4][2], afA[2][2], afB[2][2];
  auto READ_B = [&](int buf) {
#pragma unroll
    for (int n = 0; n < 4; ++n) {
      int row = (wn & 1) * 64 + n * 16 + lr;
#pragma unroll
      for (int kk = 0; kk < 2; ++kk)
        bfr[n][kk] = *(const bf16x8*)(&BS[buf][wn >> 1]
                                         [row * 64 + (((kk * 4 + hi) ^ (row & 7)) << 3)]);
    }
  };
  auto READ_A_TO = [&](bf16x8(&dst)[2][2], int buf, int q) {
#pragma unroll
    for (int mm = 0; mm < 2; ++mm) {
      int row = (q * 2 + mm) * 16 + lr;
#pragma unroll
      for (int kk = 0; kk < 2; ++kk)
        dst[mm][kk] = *(const bf16x8*)(&AS[buf][wm]
                                          [row * 64 + (((kk * 4 + hi) ^ (row & 7)) << 3)]);
    }
  };

#define MFMA16(q, AF)                                                          \
  do {                                                                         \
    _Pragma("unroll") for (int mm = 0; mm < 2; ++mm)                           \
        _Pragma("unroll") for (int n = 0; n < 4; ++n)                          \
        _Pragma("unroll") for (int kk = 0; kk < 2; ++kk)                       \
            acc[(q) * 2 + mm][n] = __builtin_amdgcn_mfma_f32_16x16x32_bf16(    \
                AF[mm][kk], bfr[n][kk], acc[(q) * 2 + mm][n], 0, 0, 0);        \
  } while (0)

  STAGE_A(0, 0);
  STAGE_B(0, 0, 0); STAGE_B(0, 0, 1);
  STAGE_B(1, 1, 0); STAGE_B(1, 1, 1);
  VMCNT(4);
  SBAR();

  for (int i = 0; i < NI; ++i) {
    int t = 2 * i;
    READ_B(0); READ_A_TO(afA, 0, 0); READ_A_TO(afB, 0, 1);
    STAGE_A(1, t + 1);
    SBAR(); LGKM0();
    __builtin_amdgcn_s_setprio(1); MFMA16(0, afA); MFMA16(1, afB);
    __builtin_amdgcn_s_setprio(0);
    SBAR();
    READ_A_TO(afA, 0, 2); READ_A_TO(afB, 0, 3);
    STAGE_B(0, t + 2, 0); STAGE_B(0, t + 2, 1);
    SBAR(); LGKM0();
    __builtin_amdgcn_s_setprio(1); MFMA16(2, afA); MFMA16(3, afB);
    __builtin_amdgcn_s_setprio(0);
    VMCNT(4);
    SBAR();
    READ_B(1); READ_A_TO(afA, 1, 0); READ_A_TO(afB, 1, 1);
    STAGE_A(0, t + 2);
    SBAR(); LGKM0();
    __builtin_amdgcn_s_setprio(1); MFMA16(0, afA); MFMA16(1, afB);
    __builtin_amdgcn_s_setprio(0);
    SBAR();
    READ_A_TO(afA, 1, 2); READ_A_TO(afB, 1, 3);
    STAGE_B(1, t + 3, 0); STAGE_B(1, t + 3, 1);
    SBAR(); LGKM0();
    __builtin_amdgcn_s_setprio(1); MFMA16(2, afA); MFMA16(3, afB);
    __builtin_amdgcn_s_setprio(0);
    VMCNT(4);
    SBAR();
  }

  VMCNT(0);
  SBAR();

#pragma unroll
  for (int m = 0; m < 8; ++m) {
    int row_base = m0 + wm * 128 + m * 16 + hi * 4;
#pragma unroll
    for (int n = 0; n < 4; ++n) {
      int col = n0 + wn * 64 + n * 16 + lr;
#pragma unroll
      for (int j = 0; j < 4; ++j) {
        float v = acc[m][n][j];
        if constexpr (sizeof(OutT) == 2)
          C[(size_t)(row_base + j) * N + col] = (OutT)__float2bfloat16(v);
        else
          C[(size_t)(row_base + j) * N + col] = (OutT)v;
      }
    }
  }
#undef MFMA16
}

// ---------------------------------------------------------------- flash attn v5
// 4 waves x 64 q-rows (mi=2 row-groups of 32) = 256 q/block, 512 blocks.
// Each K/V LDS fragment read feeds TWO MFMAs (one per mi) -> FLOP/LDS-byte
// doubles vs v3 (which was LDS-read-pipe bound at ~11% MfmaUtil).
// Same verified 32x32 swapped-QK/PV algebra; fused Q-RoPE; exp2 softmax;
// defer-max; 4-way tree reductions. launch_bounds(256,1): ~300 VGPR, no spill.
static __device__ inline u32 cvtpk_bf16(float a, float b) {
  u32 r;
  asm("v_cvt_pk_bf16_f32 %0, %1, %2" : "=v"(r) : "v"(a), "v"(b));
  return r;
}

__global__ __launch_bounds__(256, 1) void flash_attn3(const bf16* __restrict__ Q,
                                                      const bf16* __restrict__ K,
                                                      const bf16* __restrict__ VT,
                                                      const float* __restrict__ tab,
                                                      bf16* __restrict__ AO) {
  __shared__ bf16 Kbuf[2][64 * 128];
  __shared__ bf16 Vbuf[2][128 * 64];

  // 512 blocks: kvh = bid&7 -> same (b,kvh) K/V on one XCD's L2
  int bid = blockIdx.x;
  int b = bid >> 8;
  int i = (bid >> 3) & 31;
  int kvh = bid & 7;
  int hq = i >> 3;
  int qt = 7 - (i & 7);  // heavy q-tiles first
  int h = kvh * 4 + hq;

  const int tid = threadIdx.x;
  const int lane = tid & 63, w = tid >> 6;  // 4 waves
  const int ql = lane & 31, hi = lane >> 5;
  const int qrow0 = qt * 256 + w * 64;  // wave covers 64 q-rows (2 mi-groups)
  const int nt = 4 * qt + 4;

  const bf16* Kg0 = K + (size_t)b * 2048 * 6144 + kvh * 128;
  const bf16* Vg0 = VT + (size_t)(b * 8 + kvh) * 128 * 2048;

  // Q fragments with fused RoPE + scale (log2e/sqrt(d)), per mi-group
  bf16x8 qf[2][8];
#pragma unroll
  for (int mi = 0; mi < 2; ++mi) {
    int tpos = qrow0 + mi * 32 + ql;
    const bf16* qb = Q + (size_t)(b * 2048 + tpos) * 6144 + h * 128 + hi * 8;
    const float* tb = tab + (size_t)tpos * 128;
    const float QS = 1.4426950408889634f * 0.08838834764831845f;
#pragma unroll
    for (int dc = 0; dc < 8; ++dc) {
      union { bf16x8 v; u16 s[8]; } in;
      in.v = *(const bf16x8*)(qb + dc * 16);
      union { u32 u[4]; bf16x8 v; } o;
#pragma unroll
      for (int p = 0; p < 4; ++p) {
        int ii = dc * 8 + hi * 4 + p;
        float2 cs = *(const float2*)(tb + 2 * ii);
        float xr = __uint_as_float((u32)in.s[2 * p] << 16);
        float xi = __uint_as_float((u32)in.s[2 * p + 1] << 16);
        o.u[p] = cvtpk_bf16((xr * cs.x - xi * cs.y) * QS,
                            (xr * cs.y + xi * cs.x) * QS);
      }
      qf[mi][dc] = o.v;
    }
  }

  f32x16 O[2][4];
  float m_[2], l_[2];
#pragma unroll
  for (int mi = 0; mi < 2; ++mi) {
    m_[mi] = -1e30f;
    l_[mi] = 0.f;
#pragma unroll
    for (int d4 = 0; d4 < 4; ++d4)
#pragma unroll
      for (int e = 0; e < 16; ++e) O[mi][d4][e] = 0.f;
  }

  auto STAGE = [&](int buf, int kv0) {
    bf16* Ks = &Kbuf[buf][0];
    bf16* Vs = &Vbuf[buf][0];
    const bf16* Kg = Kg0 + (size_t)kv0 * 6144;
    const bf16* Vg = Vg0 + kv0;
#pragma unroll
    for (int it = 0; it < 4; ++it) {  // K: 64 rows x 16 chunks of 16B
      int s = it * 256 + tid;
      int row = s >> 4, c = s & 15;
      GLD16(Kg + (size_t)row * 6144 + ((c ^ (row & 7)) << 3), Ks + s * 8);
    }
#pragma unroll
    for (int it = 0; it < 4; ++it) {  // VT: 128 rows x 8 chunks of 16B
      int s = it * 256 + tid;
      int row = s >> 3, c = s & 7;
      GLD16(Vg + (size_t)row * 2048 + ((c ^ (row & 7)) << 3), Vs + s * 8);
    }
  };

  STAGE(0, 0);
  __syncthreads();

  for (int t = 0; t < nt; ++t) {
    int kv0 = t * 64;
    if (t + 1 < nt) STAGE((t + 1) & 1, kv0 + 64);

    if (kv0 <= qrow0 + 63) {
      const bf16* Ks = &Kbuf[t & 1][0];
      const bf16* Vs = &Vbuf[t & 1][0];

      // ---- S^T = K . Q^T : each kf read feeds both mi-groups
      f32x16 Sx[2][2];
#pragma unroll
      for (int mi = 0; mi < 2; ++mi)
#pragma unroll
        for (int cb = 0; cb < 2; ++cb)
#pragma unroll
          for (int e = 0; e < 16; ++e) Sx[mi][cb][e] = 0.f;

      __builtin_amdgcn_s_setprio(1);
#pragma unroll
      for (int cb = 0; cb < 2; ++cb) {
        int krow = cb * 32 + ql;
#pragma unroll
        for (int dc = 0; dc < 8; ++dc) {
          bf16x8 kf = *(const bf16x8*)(Ks + krow * 128 +
                                       (((dc * 2 + hi) ^ (ql & 7)) << 3));
          Sx[0][cb] = __builtin_amdgcn_mfma_f32_32x32x16_bf16(kf, qf[0][dc],
                                                              Sx[0][cb], 0, 0, 0);
          Sx[1][cb] = __builtin_amdgcn_mfma_f32_32x32x16_bf16(kf, qf[1][dc],
                                                              Sx[1][cb], 0, 0, 0);
        }
      }
      __builtin_amdgcn_s_setprio(0);

      bf16x8 pb[2][4];
#pragma unroll
      for (int mi = 0; mi < 2; ++mi) {
        int q = qrow0 + mi * 32 + ql;
        if (kv0 + 63 > qrow0 + mi * 32) {
#pragma unroll
          for (int cb = 0; cb < 2; ++cb)
#pragma unroll
            for (int r = 0; r < 16; ++r) {
              int kv = kv0 + cb * 32 + (r & 3) + 8 * (r >> 2) + 4 * hi;
              if (kv > q) Sx[mi][cb][r] = -1e30f;
            }
        }
        // 4-way tree max
        float x0 = -1e30f, x1 = -1e30f, x2 = -1e30f, x3 = -1e30f;
#pragma unroll
        for (int cb = 0; cb < 2; ++cb)
#pragma unroll
          for (int r = 0; r < 16; r += 4) {
            x0 = fmaxf(x0, Sx[mi][cb][r + 0]);
            x1 = fmaxf(x1, Sx[mi][cb][r + 1]);
            x2 = fmaxf(x2, Sx[mi][cb][r + 2]);
            x3 = fmaxf(x3, Sx[mi][cb][r + 3]);
          }
        float pm = fmaxf(fmaxf(x0, x1), fmaxf(x2, x3));
        pm = fmaxf(pm, __shfl_xor(pm, 32));

        if (!__all(pm - m_[mi] <= 11.5416f)) {  // defer-max (8*log2e)
          float nm = fmaxf(m_[mi], pm);
          float rs = exp2f(m_[mi] - nm);
          m_[mi] = nm;
          l_[mi] *= rs;
#pragma unroll
          for (int d4 = 0; d4 < 4; ++d4)
#pragma unroll
            for (int e = 0; e < 16; ++e) O[mi][d4][e] *= rs;
        }
        float s0 = 0.f, s1 = 0.f, s2 = 0.f, s3 = 0.f;
#pragma unroll
        for (int cb = 0; cb < 2; ++cb)
#pragma unroll
          for (int r = 0; r < 16; r += 4) {
            float p0 = exp2f(Sx[mi][cb][r + 0] - m_[mi]);
            float p1 = exp2f(Sx[mi][cb][r + 1] - m_[mi]);
            float p2 = exp2f(Sx[mi][cb][r + 2] - m_[mi]);
            float p3 = exp2f(Sx[mi][cb][r + 3] - m_[mi]);
            Sx[mi][cb][r + 0] = p0; Sx[mi][cb][r + 1] = p1;
            Sx[mi][cb][r + 2] = p2; Sx[mi][cb][r + 3] = p3;
            s0 += p0; s1 += p1; s2 += p2; s3 += p3;
          }
        float ps = (s0 + s1) + (s2 + s3);
        ps += __shfl_xor(ps, 32);
        l_[mi] += ps;

#pragma unroll
        for (int kb = 0; kb < 4; ++kb) {
          int cb = kb >> 1, r0 = 8 * (kb & 1);
          u32 Av = cvtpk_bf16(Sx[mi][cb][r0 + 0], Sx[mi][cb][r0 + 1]);
          u32 Bv = cvtpk_bf16(Sx[mi][cb][r0 + 2], Sx[mi][cb][r0 + 3]);
          u32 Cv = cvtpk_bf16(Sx[mi][cb][r0 + 4], Sx[mi][cb][r0 + 5]);
          u32 Dv = cvtpk_bf16(Sx[mi][cb][r0 + 6], Sx[mi][cb][r0 + 7]);
          u32 sA = (u32)__shfl_xor((int)Av, 32);
          u32 sB = (u32)__shfl_xor((int)Bv, 32);
          u32 sC = (u32)__shfl_xor((int)Cv, 32);
          u32 sD = (u32)__shfl_xor((int)Dv, 32);
          union { u32 u[4]; bf16x8 v; } pk;
          pk.u[0] = hi ? sC : Av;
          pk.u[1] = hi ? sD : Bv;
          pk.u[2] = hi ? Cv : sA;
          pk.u[3] = hi ? Dv : sB;
          pb[mi][kb] = pk.v;
        }
      }

      // ---- O^T += VT . P^T : each vf read feeds both mi-groups
      __builtin_amdgcn_s_setprio(1);
#pragma unroll
      for (int d4 = 0; d4 < 4; ++d4) {
        int vrow = d4 * 32 + ql;
#pragma unroll
        for (int kb = 0; kb < 4; ++kb) {
          bf16x8 vf = *(const bf16x8*)(Vs + vrow * 64 +
                                       (((kb * 2 + hi) ^ (ql & 7)) << 3));
          O[0][d4] = __builtin_amdgcn_mfma_f32_32x32x16_bf16(vf, pb[0][kb],
                                                             O[0][d4], 0, 0, 0);
          O[1][d4] = __builtin_amdgcn_mfma_f32_32x32x16_bf16(vf, pb[1][kb],
                                                             O[1][d4], 0, 0, 0);
        }
      }
      __builtin_amdgcn_s_setprio(0);
    }
    __syncthreads();
  }

#pragma unroll
  for (int mi = 0; mi < 2; ++mi) {
    float inv = 1.0f / l_[mi];
    bf16* outp =
        AO + (size_t)(b * 2048 + qrow0 + mi * 32 + ql) * 4096 + h * 128;
#pragma unroll
    for (int d4 = 0; d4 < 4; ++d4)
#pragma unroll
      for (int rg = 0; rg < 4; ++rg) {
        union { u16 s[4]; unsigned long long v; } pk;
#pragma unroll
        for (int j = 0; j < 4; ++j)
          pk.s[j] =
              __bfloat16_as_ushort(__float2bfloat16(O[mi][d4][rg * 4 + j] * inv));
        *(unsigned long long*)(outp + d4 * 32 + rg * 8 + hi * 4) = pk.v;
      }
  }
}

// ---------------------------------------------------------------- launch
extern "C" void kernel_launch(void* const* d_in, const int* in_sizes, int n_in,
                              void* d_out, int out_size, void* d_ws,
                              size_t ws_size, hipStream_t stream) {
  const float* x = (const float*)d_in[0];
  const float* wq = (const float*)d_in[1];
  const float* wk = (const float*)d_in[2];
  const float* wv = (const float*)d_in[3];
  const float* wo = (const float*)d_in[4];

  char* ws = (char*)d_ws;
  bf16* xb    = (bf16*)(ws + 0);           // 32 MB — reused as AOb
  bf16* WqkvT = (bf16*)(ws + 33554432);    // 48 MB (6144x4096)
  bf16* WoT   = (bf16*)(ws + 83886080);    // 32 MB
  bf16* QKV   = (bf16*)(ws + 117440512);   // 48 MB (4096x6144)
  bf16* VTb   = (bf16*)(ws + 167772160);   //  8 MB (16x128x2048)
  float* tab  = (float*)(ws + 176160768);  //  1 MB
  bf16* AOb   = xb;

  convert_f32_bf16<<<16384, 256, 0, stream>>>(x, xb);
  transpose_f32_bf16<<<dim3(128, 128), 256, 0, stream>>>(wq, WqkvT, 4096, 4096);
  transpose_f32_bf16<<<dim3(32, 128), 256, 0, stream>>>(
      wk, WqkvT + (size_t)4096 * 4096, 4096, 1024);
  transpose_f32_bf16<<<dim3(32, 128), 256, 0, stream>>>(
      wv, WqkvT + (size_t)5120 * 4096, 4096, 1024);
  transpose_f32_bf16<<<dim3(128, 128), 256, 0, stream>>>(wo, WoT, 4096, 4096);
  rope_table_k<<<512, 256, 0, stream>>>(tab);

  // fused QKV projection: 256^2 tiles, 384 blocks — measured best (242 us)
  gemm_bt8<bf16><<<dim3(24, 16), 512, 0, stream>>>(xb, WqkvT, QKV, 4096, 6144,
                                                   4096);

  // K gets RoPE in-place; Q's RoPE is fused into flash_attn3
  rope_apply<<<8192, 256, 0, stream>>>(QKV + 4096, tab, 8, 6144, 1.0f);

  transpose_v<<<dim3(64, 4, 16), 256, 0, stream>>>(QKV + 5120, VTb);

  // 512 blocks x 256 threads (4 waves x 64 q-rows, mi=2 K/V-read sharing)
  flash_attn3<<<512, 256, 0, stream>>>(QKV, QKV + 4096, VTb, tab, AOb);

  // O-projection (256 blocks): 256^2 kernel — measured best
  gemm_bt8<float><<<dim3(16, 16), 512, 0, stream>>>(AOb, WoT, (float*)d_out,
                                                    4096, 4096, 4096);
}

// Round 16
// 597.708 us; speedup vs baseline: 1.1671x; 1.1671x over previous
//
#include <hip/hip_runtime.h>
#include <hip/hip_bf16.h>
#include <math.h>

typedef __hip_bfloat16 bf16;
typedef short bf16x8 __attribute__((ext_vector_type(8)));
typedef float f32x4 __attribute__((ext_vector_type(4)));
typedef float f32x16 __attribute__((ext_vector_type(16)));
typedef unsigned int u32;
typedef unsigned short u16;

#define GLD16(g, l)                                                            \
  __builtin_amdgcn_global_load_lds(                                            \
      (const __attribute__((address_space(1))) void*)(g),                      \
      (__attribute__((address_space(3))) void*)(l), 16, 0, 0)

#define SBAR() __builtin_amdgcn_s_barrier()
#define VMCNT(n) asm volatile("s_waitcnt vmcnt(" #n ")")
#define LGKM0() asm volatile("s_waitcnt lgkmcnt(0)")

// ------------------------------------------------------- f32 -> bf16 copy
__global__ void convert_f32_bf16(const float* __restrict__ in,
                                 bf16* __restrict__ out) {
  size_t i = ((size_t)blockIdx.x * 256 + threadIdx.x) * 4;
  float4 v = *(const float4*)(in + i);
  out[i + 0] = __float2bfloat16(v.x);
  out[i + 1] = __float2bfloat16(v.y);
  out[i + 2] = __float2bfloat16(v.z);
  out[i + 3] = __float2bfloat16(v.w);
}

// ------------------------------------------------- fused prep (one launch):
// 4 weight transposes (f32 -> bf16, 32x32 tiles) + RoPE cos/sin table.
// Flat grid: [0,16384) wq | [16384,20480) wk | [20480,24576) wv |
// [24576,40960) wo | [40960,41472) rope table.
__device__ void transpose_tile(const float* __restrict__ in,
                               bf16* __restrict__ out, int R, int C, int bx,
                               int by) {
  __shared__ bf16 tile[32][33];
  int tx = threadIdx.x & 31, ty = threadIdx.x >> 5;
  int c0 = bx * 32, r0 = by * 32;
#pragma unroll
  for (int i = 0; i < 32; i += 8)
    tile[ty + i][tx] = __float2bfloat16(in[(size_t)(r0 + ty + i) * C + c0 + tx]);
  __syncthreads();
#pragma unroll
  for (int i = 0; i < 32; i += 8)
    out[(size_t)(c0 + ty + i) * R + r0 + tx] = tile[tx][ty + i];
}

__global__ void prep_weights(const float* __restrict__ wq,
                             const float* __restrict__ wk,
                             const float* __restrict__ wv,
                             const float* __restrict__ wo,
                             bf16* __restrict__ WqkvT, bf16* __restrict__ WoT,
                             float* __restrict__ tab) {
  int bid = blockIdx.x;
  if (bid < 16384) {
    transpose_tile(wq, WqkvT, 4096, 4096, bid & 127, bid >> 7);
  } else if (bid < 20480) {
    int l = bid - 16384;
    transpose_tile(wk, WqkvT + (size_t)4096 * 4096, 4096, 1024, l & 31, l >> 5);
  } else if (bid < 24576) {
    int l = bid - 20480;
    transpose_tile(wv, WqkvT + (size_t)5120 * 4096, 4096, 1024, l & 31, l >> 5);
  } else if (bid < 40960) {
    int l = bid - 24576;
    transpose_tile(wo, WoT, 4096, 4096, l & 127, l >> 7);
  } else {
    int idx = (bid - 40960) * 256 + threadIdx.x;  // t*64 + i
    int t = idx >> 6, i = idx & 63;
    float theta = powf(10000.0f, -2.0f * (float)i / 128.0f);
    float ang = (float)t * theta;
    tab[idx * 2 + 0] = cosf(ang);
    tab[idx * 2 + 1] = sinf(ang);
  }
}

// --------------------------------------- fused post-QKV (one launch):
// K-RoPE in place (QKV cols 4096..5119) + V transpose (cols 5120..6143 ->
// VT[16][128][2048]). Disjoint column ranges, independent.
// Flat grid: [0,8192) ropeK | [8192,12288) transpose_v.
__global__ void post_qkv(bf16* __restrict__ QKV, const float* __restrict__ tab,
                         bf16* __restrict__ VT) {
  int bid = blockIdx.x;
  if (bid < 8192) {
    size_t idx = (size_t)bid * 256 + threadIdx.x;  // rows*8heads*64
    int i = (int)(idx & 63);
    size_t rest = idx >> 6;
    int h = (int)(rest & 7);
    size_t r = rest >> 3;
    int t = (int)(r & 2047);
    float c = tab[(t * 64 + i) * 2 + 0];
    float s = tab[(t * 64 + i) * 2 + 1];
    bf16* p = QKV + r * 6144 + 4096 + h * 128 + 2 * i;
    float xr = __bfloat162float(p[0]), xi = __bfloat162float(p[1]);
    p[0] = __float2bfloat16(xr * c - xi * s);
    p[1] = __float2bfloat16(xr * s + xi * c);
  } else {
    __shared__ bf16 tile[32][33];
    int l = bid - 8192;
    int x = l & 63, y = (l >> 6) & 3, s = l >> 8;
    int b = s >> 3, kvh = s & 7;
    int t0 = x * 32, d0 = y * 32;
    int tx = threadIdx.x & 31, ty = threadIdx.x >> 5;
#pragma unroll
    for (int i = 0; i < 32; i += 8)
      tile[ty + i][tx] = QKV[(size_t)(b * 2048 + t0 + ty + i) * 6144 + 5120 +
                             kvh * 128 + d0 + tx];
    __syncthreads();
#pragma unroll
    for (int i = 0; i < 32; i += 8)
      VT[((size_t)s * 128 + d0 + ty + i) * 2048 + t0 + tx] = tile[tx][ty + i];
  }
}

// ------------------------------------------------ GEMM 4-phase 256x256 BK=64
// (measured best: QKV 242 us at 384 blocks, O-proj at 256 blocks)
template <typename OutT>
__global__ __launch_bounds__(512, 2) void gemm_bt8(const bf16* __restrict__ A,
                                                   const bf16* __restrict__ BT,
                                                   OutT* __restrict__ C, int M,
                                                   int N, int K) {
  __shared__ bf16 AS[2][2][128 * 64];
  __shared__ bf16 BS[2][2][128 * 64];

  const int tid = threadIdx.x;
  const int lane = tid & 63;
  const int w = tid >> 6, wm = w >> 2, wn = w & 3;
  const int lr = lane & 15, hi = lane >> 4;

  int gx = gridDim.x;
  int nwg = gx * gridDim.y;
  int bid = blockIdx.y * gx + blockIdx.x;
  int swz = (bid & 7) * (nwg >> 3) + (bid >> 3);
  const int m0 = (swz / gx) * 256, n0 = (swz % gx) * 256;

  const int NKT = K >> 6;
  const int NI = K >> 7;
  const int srow = tid >> 3;
  const int scol = ((tid & 7) ^ (srow & 7)) << 3;

  f32x4 acc[8][4];
#pragma unroll
  for (int m = 0; m < 8; ++m)
#pragma unroll
    for (int n = 0; n < 4; ++n)
#pragma unroll
      for (int j = 0; j < 4; ++j) acc[m][n][j] = 0.f;

  auto STAGE_A = [&](int buf, int kt) {
    int kk0 = (kt < NKT) ? kt * 64 : 0;
#pragma unroll
    for (int hs = 0; hs < 4; ++hs) {
      int ha = hs >> 1, sa = hs & 1;
      const bf16* g = A + (size_t)(m0 + ha * 128 + sa * 64 + srow) * K + kk0 + scol;
      GLD16(g, &AS[buf][ha][(sa * 64 + srow) * 64 + (tid & 7) * 8]);
    }
  };
  auto STAGE_B = [&](int buf, int kt, int half) {
    int kk0 = (kt < NKT) ? kt * 64 : 0;
#pragma unroll
    for (int sa = 0; sa < 2; ++sa) {
      const bf16* g =
          BT + (size_t)(n0 + half * 128 + sa * 64 + srow) * K + kk0 + scol;
      GLD16(g, &BS[buf][half][(sa * 64 + srow) * 64 + (tid & 7) * 8]);
    }
  };

  bf16x8 bfr[4][2], afA[2][2], afB[2][2];
  auto READ_B = [&](int buf) {
#pragma unroll
    for (int n = 0; n < 4; ++n) {
      int row = (wn & 1) * 64 + n * 16 + lr;
#pragma unroll
      for (int kk = 0; kk < 2; ++kk)
        bfr[n][kk] = *(const bf16x8*)(&BS[buf][wn >> 1]
                                         [row * 64 + (((kk * 4 + hi) ^ (row & 7)) << 3)]);
    }
  };
  auto READ_A_TO = [&](bf16x8(&dst)[2][2], int buf, int q) {
#pragma unroll
    for (int mm = 0; mm < 2; ++mm) {
      int row = (q * 2 + mm) * 16 + lr;
#pragma unroll
      for (int kk = 0; kk < 2; ++kk)
        dst[mm][kk] = *(const bf16x8*)(&AS[buf][wm]
                                          [row * 64 + (((kk * 4 + hi) ^ (row & 7)) << 3)]);
    }
  };

#define MFMA16(q, AF)                                                          \
  do {                                                                         \
    _Pragma("unroll") for (int mm = 0; mm < 2; ++mm)                           \
        _Pragma("unroll") for (int n = 0; n < 4; ++n)                          \
        _Pragma("unroll") for (int kk = 0; kk < 2; ++kk)                       \
            acc[(q) * 2 + mm][n] = __builtin_amdgcn_mfma_f32_16x16x32_bf16(    \
                AF[mm][kk], bfr[n][kk], acc[(q) * 2 + mm][n], 0, 0, 0);        \
  } while (0)

  STAGE_A(0, 0);
  STAGE_B(0, 0, 0); STAGE_B(0, 0, 1);
  STAGE_B(1, 1, 0); STAGE_B(1, 1, 1);
  VMCNT(4);
  SBAR();

  for (int i = 0; i < NI; ++i) {
    int t = 2 * i;
    READ_B(0); READ_A_TO(afA, 0, 0); READ_A_TO(afB, 0, 1);
    STAGE_A(1, t + 1);
    SBAR(); LGKM0();
    __builtin_amdgcn_s_setprio(1); MFMA16(0, afA); MFMA16(1, afB);
    __builtin_amdgcn_s_setprio(0);
    SBAR();
    READ_A_TO(afA, 0, 2); READ_A_TO(afB, 0, 3);
    STAGE_B(0, t + 2, 0); STAGE_B(0, t + 2, 1);
    SBAR(); LGKM0();
    __builtin_amdgcn_s_setprio(1); MFMA16(2, afA); MFMA16(3, afB);
    __builtin_amdgcn_s_setprio(0);
    VMCNT(4);
    SBAR();
    READ_B(1); READ_A_TO(afA, 1, 0); READ_A_TO(afB, 1, 1);
    STAGE_A(0, t + 2);
    SBAR(); LGKM0();
    __builtin_amdgcn_s_setprio(1); MFMA16(0, afA); MFMA16(1, afB);
    __builtin_amdgcn_s_setprio(0);
    SBAR();
    READ_A_TO(afA, 1, 2); READ_A_TO(afB, 1, 3);
    STAGE_B(1, t + 3, 0); STAGE_B(1, t + 3, 1);
    SBAR(); LGKM0();
    __builtin_amdgcn_s_setprio(1); MFMA16(2, afA); MFMA16(3, afB);
    __builtin_amdgcn_s_setprio(0);
    VMCNT(4);
    SBAR();
  }

  VMCNT(0);
  SBAR();

#pragma unroll
  for (int m = 0; m < 8; ++m) {
    int row_base = m0 + wm * 128 + m * 16 + hi * 4;
#pragma unroll
    for (int n = 0; n < 4; ++n) {
      int col = n0 + wn * 64 + n * 16 + lr;
#pragma unroll
      for (int j = 0; j < 4; ++j) {
        float v = acc[m][n][j];
        if constexpr (sizeof(OutT) == 2)
          C[(size_t)(row_base + j) * N + col] = (OutT)__float2bfloat16(v);
        else
          C[(size_t)(row_base + j) * N + col] = (OutT)v;
      }
    }
  }
#undef MFMA16
}

// ---------------------------------------------------------------- flash attn
// R11 configuration (measured best, 211 us): 8 waves x 32 q-rows (256 q/block),
// 512 blocks, mfma_32x32x16, fused Q-RoPE, swapped QK/PV, reg-P via
// cvt_pk+shfl_xor(32), exp2 softmax, defer-max, setprio.
static __device__ inline u32 cvtpk_bf16(float a, float b) {
  u32 r;
  asm("v_cvt_pk_bf16_f32 %0, %1, %2" : "=v"(r) : "v"(a), "v"(b));
  return r;
}

__global__ __launch_bounds__(512) void flash_attn3(const bf16* __restrict__ Q,
                                                   const bf16* __restrict__ K,
                                                   const bf16* __restrict__ VT,
                                                   const float* __restrict__ tab,
                                                   bf16* __restrict__ AO) {
  __shared__ bf16 Kbuf[2][64 * 128];
  __shared__ bf16 Vbuf[2][128 * 64];

  int bid = blockIdx.x;
  int b = bid >> 8;
  int i = (bid >> 3) & 31;
  int kvh = bid & 7;
  int hq = i >> 3;
  int qt = 7 - (i & 7);
  int h = kvh * 4 + hq;

  const int tid = threadIdx.x;
  const int lane = tid & 63, w = tid >> 6;
  const int ql = lane & 31, hi = lane >> 5;
  const int qrow0 = qt * 256 + w * 32;
  const int nt = 4 * qt + 4;

  const bf16* Kg0 = K + (size_t)b * 2048 * 6144 + kvh * 128;
  const bf16* Vg0 = VT + (size_t)(b * 8 + kvh) * 128 * 2048;

  bf16x8 qf[8];
  {
    int tpos = qrow0 + ql;
    const bf16* qb = Q + (size_t)(b * 2048 + tpos) * 6144 + h * 128 + hi * 8;
    const float* tb = tab + (size_t)tpos * 128;
    const float QS = 1.4426950408889634f * 0.08838834764831845f;
#pragma unroll
    for (int dc = 0; dc < 8; ++dc) {
      union { bf16x8 v; u16 s[8]; } in;
      in.v = *(const bf16x8*)(qb + dc * 16);
      union { u32 u[4]; bf16x8 v; } o;
#pragma unroll
      for (int p = 0; p < 4; ++p) {
        int ii = dc * 8 + hi * 4 + p;
        float2 cs = *(const float2*)(tb + 2 * ii);
        float xr = __uint_as_float((u32)in.s[2 * p] << 16);
        float xi = __uint_as_float((u32)in.s[2 * p + 1] << 16);
        o.u[p] = cvtpk_bf16((xr * cs.x - xi * cs.y) * QS,
                            (xr * cs.y + xi * cs.x) * QS);
      }
      qf[dc] = o.v;
    }
  }

  f32x16 O[4];
#pragma unroll
  for (int d4 = 0; d4 < 4; ++d4)
#pragma unroll
    for (int e = 0; e < 16; ++e) O[d4][e] = 0.f;
  float m_ = -1e30f, l_ = 0.f;

  auto STAGE = [&](int buf, int kv0) {
    bf16* Ks = &Kbuf[buf][0];
    bf16* Vs = &Vbuf[buf][0];
    const bf16* Kg = Kg0 + (size_t)kv0 * 6144;
    const bf16* Vg = Vg0 + kv0;
#pragma unroll
    for (int it = 0; it < 2; ++it) {
      int s = it * 512 + tid;
      int row = s >> 4, c = s & 15;
      GLD16(Kg + (size_t)row * 6144 + ((c ^ (row & 7)) << 3), Ks + s * 8);
    }
#pragma unroll
    for (int it = 0; it < 2; ++it) {
      int s = it * 512 + tid;
      int row = s >> 3, c = s & 7;
      GLD16(Vg + (size_t)row * 2048 + ((c ^ (row & 7)) << 3), Vs + s * 8);
    }
  };

  STAGE(0, 0);
  __syncthreads();

  for (int t = 0; t < nt; ++t) {
    int kv0 = t * 64;
    if (t + 1 < nt) STAGE((t + 1) & 1, kv0 + 64);

    if (kv0 <= qrow0 + 31) {
      const bf16* Ks = &Kbuf[t & 1][0];
      const bf16* Vs = &Vbuf[t & 1][0];

      f32x16 Sx[2];
#pragma unroll
      for (int cb = 0; cb < 2; ++cb)
#pragma unroll
        for (int e = 0; e < 16; ++e) Sx[cb][e] = 0.f;

      __builtin_amdgcn_s_setprio(1);
#pragma unroll
      for (int cb = 0; cb < 2; ++cb) {
        int krow = cb * 32 + ql;
#pragma unroll
        for (int dc = 0; dc < 8; ++dc) {
          bf16x8 kf = *(const bf16x8*)(Ks + krow * 128 +
                                       (((dc * 2 + hi) ^ (ql & 7)) << 3));
          Sx[cb] = __builtin_amdgcn_mfma_f32_32x32x16_bf16(kf, qf[dc], Sx[cb],
                                                           0, 0, 0);
        }
      }
      __builtin_amdgcn_s_setprio(0);

      int q = qrow0 + ql;
      bool domask = (kv0 + 63 > qrow0);
      if (domask) {
#pragma unroll
        for (int cb = 0; cb < 2; ++cb)
#pragma unroll
          for (int r = 0; r < 16; ++r) {
            int kv = kv0 + cb * 32 + (r & 3) + 8 * (r >> 2) + 4 * hi;
            if (kv > q) Sx[cb][r] = -1e30f;
          }
      }
      float pm = -1e30f;
#pragma unroll
      for (int cb = 0; cb < 2; ++cb)
#pragma unroll
        for (int r = 0; r < 16; ++r) pm = fmaxf(pm, Sx[cb][r]);
      pm = fmaxf(pm, __shfl_xor(pm, 32));

      if (!__all(pm - m_ <= 11.5416f)) {
        float nm = fmaxf(m_, pm);
        float rs = exp2f(m_ - nm);
        m_ = nm;
        l_ *= rs;
#pragma unroll
        for (int d4 = 0; d4 < 4; ++d4)
#pragma unroll
          for (int e = 0; e < 16; ++e) O[d4][e] *= rs;
      }
      float ps = 0.f;
#pragma unroll
      for (int cb = 0; cb < 2; ++cb)
#pragma unroll
        for (int r = 0; r < 16; ++r) {
          float p = exp2f(Sx[cb][r] - m_);
          Sx[cb][r] = p;
          ps += p;
        }
      ps += __shfl_xor(ps, 32);
      l_ += ps;

      bf16x8 pb[4];
#pragma unroll
      for (int kb = 0; kb < 4; ++kb) {
        int cb = kb >> 1, r0 = 8 * (kb & 1);
        u32 Av = cvtpk_bf16(Sx[cb][r0 + 0], Sx[cb][r0 + 1]);
        u32 Bv = cvtpk_bf16(Sx[cb][r0 + 2], Sx[cb][r0 + 3]);
        u32 Cv = cvtpk_bf16(Sx[cb][r0 + 4], Sx[cb][r0 + 5]);
        u32 Dv = cvtpk_bf16(Sx[cb][r0 + 6], Sx[cb][r0 + 7]);
        u32 sA = (u32)__shfl_xor((int)Av, 32);
        u32 sB = (u32)__shfl_xor((int)Bv, 32);
        u32 sC = (u32)__shfl_xor((int)Cv, 32);
        u32 sD = (u32)__shfl_xor((int)Dv, 32);
        union { u32 u[4]; bf16x8 v; } pk;
        pk.u[0] = hi ? sC : Av;
        pk.u[1] = hi ? sD : Bv;
        pk.u[2] = hi ? Cv : sA;
        pk.u[3] = hi ? Dv : sB;
        pb[kb] = pk.v;
      }

      __builtin_amdgcn_s_setprio(1);
#pragma unroll
      for (int d4 = 0; d4 < 4; ++d4) {
        int vrow = d4 * 32 + ql;
#pragma unroll
        for (int kb = 0; kb < 4; ++kb) {
          bf16x8 vf = *(const bf16x8*)(Vs + vrow * 64 +
                                       (((kb * 2 + hi) ^ (ql & 7)) << 3));
          O[d4] = __builtin_amdgcn_mfma_f32_32x32x16_bf16(vf, pb[kb], O[d4], 0,
                                                          0, 0);
        }
      }
      __builtin_amdgcn_s_setprio(0);
    }
    __syncthreads();
  }

  float inv = 1.0f / l_;
  bf16* outp = AO + (size_t)(b * 2048 + qrow0 + ql) * 4096 + h * 128;
#pragma unroll
  for (int d4 = 0; d4 < 4; ++d4)
#pragma unroll
    for (int rg = 0; rg < 4; ++rg) {
      union { u16 s[4]; unsigned long long v; } pk;
#pragma unroll
      for (int j = 0; j < 4; ++j)
        pk.s[j] = __bfloat16_as_ushort(__float2bfloat16(O[d4][rg * 4 + j] * inv));
      *(unsigned long long*)(outp + d4 * 32 + rg * 8 + hi * 4) = pk.v;
    }
}

// ---------------------------------------------------------------- launch
extern "C" void kernel_launch(void* const* d_in, const int* in_sizes, int n_in,
                              void* d_out, int out_size, void* d_ws,
                              size_t ws_size, hipStream_t stream) {
  const float* x = (const float*)d_in[0];
  const float* wq = (const float*)d_in[1];
  const float* wk = (const float*)d_in[2];
  const float* wv = (const float*)d_in[3];
  const float* wo = (const float*)d_in[4];

  char* ws = (char*)d_ws;
  bf16* xb    = (bf16*)(ws + 0);           // 32 MB — reused as AOb
  bf16* WqkvT = (bf16*)(ws + 33554432);    // 48 MB (6144x4096)
  bf16* WoT   = (bf16*)(ws + 83886080);    // 32 MB
  bf16* QKV   = (bf16*)(ws + 117440512);   // 48 MB (4096x6144)
  bf16* VTb   = (bf16*)(ws + 167772160);   //  8 MB (16x128x2048)
  float* tab  = (float*)(ws + 176160768);  //  1 MB
  bf16* AOb   = xb;

  convert_f32_bf16<<<16384, 256, 0, stream>>>(x, xb);
  // fused: wq|wk|wv|wo transposes + RoPE table (one launch)
  prep_weights<<<41472, 256, 0, stream>>>(wq, wk, wv, wo, WqkvT, WoT, tab);

  // fused QKV projection: 256^2 tiles, 384 blocks — measured best (242 us)
  gemm_bt8<bf16><<<dim3(24, 16), 512, 0, stream>>>(xb, WqkvT, QKV, 4096, 6144,
                                                   4096);

  // fused: K-RoPE in place + V transpose (one launch)
  post_qkv<<<12288, 256, 0, stream>>>(QKV, tab, VTb);

  // attention: 512 blocks x 512 threads (8 waves x 32 q) — measured best
  flash_attn3<<<512, 512, 0, stream>>>(QKV, QKV + 4096, VTb, tab, AOb);

  // O-projection (256 blocks): 256^2 kernel — measured best
  gemm_bt8<float><<<dim3(16, 16), 512, 0, stream>>>(AOb, WoT, (float*)d_out,
                                                    4096, 4096, 4096);
}